// Round 1
// baseline (2918.037 us; speedup 1.0000x reference)
//
#include <hip/hip_runtime.h>
#include <stdint.h>

#define HH   128
#define NLAY 3
#define RR   32
#define OO   48
#define BBX  64
#define FFX  32
#define LLX  (RR + OO - 1)    /* 79  */
#define RBr  (RR * BBX)       /* 2048 */
#define N6   (6 * HH)         /* 768 */

typedef unsigned short u16;
typedef __attribute__((ext_vector_type(8))) short short8;
typedef __attribute__((ext_vector_type(4))) float f32x4;

__device__ __forceinline__ u16 f2b(float x) {
  uint32_t u = __float_as_uint(x);
  return (u16)((u + 0x7FFFu + ((u >> 16) & 1u)) >> 16);
}
__device__ __forceinline__ float sigmoidf_(float x) {
  return 1.0f / (1.0f + __expf(-x));
}
__device__ __forceinline__ float tanhf_(float x) {
  float e = __expf(2.0f * x);
  return 1.0f - 2.0f / (e + 1.0f);
}

// ---------------- prep: wavefront-shifted bf16 input ----------------
// abuf0[s][g*B+b][f] = inp[b][g][s-g][f] if 0<=s-g<O else 0
__global__ __launch_bounds__(256) void k_prep_input(const float* __restrict__ inp,
                                                    u16* __restrict__ abuf0) {
  int idx = blockIdx.x * 256 + threadIdx.x;
  if (idx >= LLX * RBr * FFX) return;
  int f   = idx & (FFX - 1);
  int row = (idx >> 5) & (RBr - 1);
  int s   = idx / (RBr * FFX);
  int g = row >> 6, b = row & 63;
  int o = s - g;
  float v = (o >= 0 && o < OO) ? inp[((b * RR + g) * OO + o) * FFX + f] : 0.0f;
  abuf0[idx] = f2b(v);
}

// ---------------- prep: weights f32 -> bf16 ----------------
__global__ __launch_bounds__(256) void k_prep_w(const float* __restrict__ Wf,
                                                const float* __restrict__ Wo,
                                                u16* __restrict__ w0,
                                                u16* __restrict__ w12) {
  int idx = blockIdx.x * 256 + threadIdx.x;
  const int n0 = N6 * 288;          // 221184
  const int n12 = 2 * N6 * 512;     // 786432
  if (idx < n0) w0[idx] = f2b(Wf[idx]);
  else if (idx < n0 + n12) w12[idx - n0] = f2b(Wo[idx - n0]);
}

// ---------------- per-layer state reset ----------------
__global__ __launch_bounds__(256) void k_reset(u16* __restrict__ hz,
                                               float* __restrict__ hrow,
                                               float* __restrict__ hcolA,
                                               float* __restrict__ hcolB) {
  int idx = blockIdx.x * 256 + threadIdx.x;
  if (idx < RBr * 256) hz[idx] = 0;
  if (idx < RBr * HH) { hrow[idx] = 0.0f; hcolA[idx] = 0.0f; hcolB[idx] = 0.0f; }
}

// ---------------- step GEMM: gates[2048][768] = Z @ W^T ----------------
// Z row layout: cols [0:256) from hz, cols [256:256+KA) from a_s.
// W is [768][K] row-major (i.e. B^T), K = 256+KA. 64x64 tile, 4 waves.
template <int KA>
__global__ __launch_bounds__(256) void k_gemm(const u16* __restrict__ hz,
                                              const u16* __restrict__ a_s,
                                              const u16* __restrict__ Wb,
                                              float* __restrict__ gates) {
  constexpr int K = 256 + KA;
  constexpr int NCH = K / 32;
  __shared__ u16 Al[64][40];
  __shared__ u16 Bl[64][40];
  const int tid = threadIdx.x;
  const int bm = blockIdx.x, bn = blockIdx.y;
  const int lane = tid & 63, wave = tid >> 6;
  const int wm = wave >> 1, wn = wave & 1;
  const int lr = tid >> 2, lc = (tid & 3) << 3;   // staging: row, col*8
  const int arow = bm * 64 + lr;
  const int brow = bn * 64 + lr;

  f32x4 z4 = {0.f, 0.f, 0.f, 0.f};
  f32x4 acc[2][2] = {{z4, z4}, {z4, z4}};

  const int kg = (lane >> 4) << 3;   // fragment k-offset: 0,8,16,24
  const int fr = lane & 15;          // fragment row/col

  for (int kc = 0; kc < NCH; ++kc) {
    const int k0 = kc << 5;
    short8 av, bv;
    if (k0 + lc < 256) av = *(const short8*)&hz[arow * 256 + k0 + lc];
    else               av = *(const short8*)&a_s[arow * KA + (k0 - 256) + lc];
    bv = *(const short8*)&Wb[brow * K + k0 + lc];
    __syncthreads();
    *(short8*)&Al[lr][lc] = av;
    *(short8*)&Bl[lr][lc] = bv;
    __syncthreads();
    short8 af0 = *(const short8*)&Al[wm * 32 + fr][kg];
    short8 af1 = *(const short8*)&Al[wm * 32 + 16 + fr][kg];
    short8 bf0 = *(const short8*)&Bl[wn * 32 + fr][kg];
    short8 bf1 = *(const short8*)&Bl[wn * 32 + 16 + fr][kg];
    acc[0][0] = __builtin_amdgcn_mfma_f32_16x16x32_bf16(af0, bf0, acc[0][0], 0, 0, 0);
    acc[0][1] = __builtin_amdgcn_mfma_f32_16x16x32_bf16(af0, bf1, acc[0][1], 0, 0, 0);
    acc[1][0] = __builtin_amdgcn_mfma_f32_16x16x32_bf16(af1, bf0, acc[1][0], 0, 0, 0);
    acc[1][1] = __builtin_amdgcn_mfma_f32_16x16x32_bf16(af1, bf1, acc[1][1], 0, 0, 0);
  }
  // C layout (verified): col = lane&15, row = (lane>>4)*4 + reg
  const int crow0 = bm * 64 + wm * 32;
  const int ccol0 = bn * 64 + wn * 32;
  const int rsub = (lane >> 4) << 2;
  const int csub = lane & 15;
  for (int fm = 0; fm < 2; ++fm)
    for (int fn = 0; fn < 2; ++fn)
      for (int j = 0; j < 4; ++j)
        gates[(size_t)(crow0 + fm * 16 + rsub + j) * N6 + (ccol0 + fn * 16 + csub)] =
            acc[fm][fn][j];
}

// ---------------- pointwise: activations + state update + stores ----------------
__global__ __launch_bounds__(256) void k_point(const float* __restrict__ gates,
                                               const float* __restrict__ bias,
                                               float* __restrict__ hrow,
                                               const float* __restrict__ hcol_in,
                                               float* __restrict__ hcol_out,
                                               u16* __restrict__ hz,
                                               u16* __restrict__ abuf_s,   // layers 0,1
                                               float* __restrict__ out_s,  // layer 2
                                               float* __restrict__ hid_row,
                                               float* __restrict__ hid_col,
                                               int s, int layer) {
  int idx = blockIdx.x * 256 + threadIdx.x;    // (row, j), 2048*128
  int j = idx & (HH - 1);
  int row = idx >> 7;
  int g = row >> 6, b = row & 63;
  float m = (g <= s && s < RR) ? 1.0f : 0.0f;
  const float* grow = gates + (size_t)row * N6;
  float ur   = sigmoidf_(grow[j]          + m * bias[j]);
  float orw  = sigmoidf_(grow[HH + j]     + m * bias[HH + j]);
  float uc   = sigmoidf_(grow[2 * HH + j] + m * bias[2 * HH + j]);
  float ocl  = sigmoidf_(grow[3 * HH + j] + m * bias[3 * HH + j]);
  float ir   = tanhf_(grow[4 * HH + j]    + m * bias[4 * HH + j]);
  float ic   = tanhf_(grow[5 * HH + j]    + m * bias[5 * HH + j]);
  float hr_old = hrow[idx];
  float hc_old = hcol_in[idx];
  float hr_n = tanhf_((1.0f - ur) * hr_old + ur * ir) * orw;
  float hc_n = tanhf_((1.0f - uc) * hc_old + uc * ic) * ocl;
  hrow[idx] = hr_n;
  int rowp = (((g + 1) & (RR - 1)) << 6) + b;  // roll: group g -> g+1 (wrap)
  hcol_out[rowp * HH + j] = hc_n;
  hz[row * 256 + j] = f2b(hr_n);
  hz[rowp * 256 + HH + j] = f2b(hc_n);
  if (out_s) {
    out_s[(size_t)row * (LLX * 256) + (size_t)s * 256 + j] = hr_n;
    out_s[(size_t)row * (LLX * 256) + (size_t)s * 256 + HH + j] = hc_n;
  } else {
    abuf_s[row * 256 + j] = f2b(hr_n);
    abuf_s[row * 256 + HH + j] = f2b(hc_n);
  }
  if (s - g == OO - 1)
    hid_row[((size_t)(b * NLAY + layer) * RR + g) * HH + j] = hr_n;
  if (g == RR - 1 && s >= RR - 1)
    hid_col[((size_t)(b * NLAY + layer) * OO + (s - (RR - 1))) * HH + j] = hc_n;
}

extern "C" void kernel_launch(void* const* d_in, const int* in_sizes, int n_in,
                              void* d_out, int out_size, void* d_ws, size_t ws_size,
                              hipStream_t stream) {
  const float* inp  = (const float*)d_in[0];
  const float* Wf   = (const float*)d_in[1];
  const float* Wo   = (const float*)d_in[2];
  const float* Bias = (const float*)d_in[3];
  float* out = (float*)d_out;

  char* ws = (char*)d_ws;
  size_t off = 0;
  auto alloc = [&](size_t bytes) -> void* {
    void* p = ws + off;
    off = (off + bytes + 255) & ~(size_t)255;
    return p;
  };
  u16*   abuf0 = (u16*)alloc((size_t)LLX * RBr * FFX * 2);   // 10.35 MB
  u16*   abuf  = (u16*)alloc((size_t)LLX * RBr * 256 * 2);   // 82.8 MB
  u16*   wb0   = (u16*)alloc((size_t)N6 * 288 * 2);
  u16*   wb12  = (u16*)alloc((size_t)2 * N6 * 512 * 2);
  float* gates = (float*)alloc((size_t)RBr * N6 * 4);
  float* hrow  = (float*)alloc((size_t)RBr * HH * 4);
  float* hcolA = (float*)alloc((size_t)RBr * HH * 4);
  float* hcolB = (float*)alloc((size_t)RBr * HH * 4);
  u16*   hz    = (u16*)alloc((size_t)RBr * 256 * 2);
  (void)ws_size; (void)in_sizes; (void)n_in; (void)out_size;

  float* out_all = out;                                  // [2048][79][256]
  float* hid_row = out + (size_t)RBr * LLX * 256;        // [64][3][32][128]
  float* hid_col = hid_row + (size_t)BBX * NLAY * RR * HH;  // [64][3][48][128]

  k_prep_input<<<(LLX * RBr * FFX) / 256, 256, 0, stream>>>(inp, abuf0);
  k_prep_w<<<(N6 * 288 + 2 * N6 * 512) / 256, 256, 0, stream>>>(Wf, Wo, wb0, wb12);

  for (int l = 0; l < NLAY; ++l) {
    k_reset<<<(RBr * 256) / 256, 256, 0, stream>>>(hz, hrow, hcolA, hcolB);
    const u16* Wb = (l == 0) ? wb0 : wb12 + (size_t)(l - 1) * N6 * 512;
    const float* bias_l = Bias + l * N6;
    for (int s = 0; s < LLX; ++s) {
      if (l == 0) {
        const u16* a_s = abuf0 + (size_t)s * RBr * FFX;
        k_gemm<32><<<dim3(32, 12), 256, 0, stream>>>(hz, a_s, Wb, gates);
      } else {
        const u16* a_s = abuf + (size_t)s * RBr * 256;
        k_gemm<256><<<dim3(32, 12), 256, 0, stream>>>(hz, a_s, Wb, gates);
      }
      float* hin  = (s & 1) ? hcolB : hcolA;
      float* hout = (s & 1) ? hcolA : hcolB;
      u16*   ab_s = (l < 2) ? abuf + (size_t)s * RBr * 256 : nullptr;
      float* o_s  = (l == 2) ? out_all : nullptr;
      k_point<<<(RBr * HH) / 256, 256, 0, stream>>>(gates, bias_l, hrow, hin, hout,
                                                    hz, ab_s, o_s, hid_row, hid_col,
                                                    s, l);
    }
  }
}

// Round 2
// 2510.413 us; speedup vs baseline: 1.1624x; 1.1624x over previous
//
#include <hip/hip_runtime.h>
#include <stdint.h>

#define HH   128
#define NLAY 3
#define RR   32
#define OO   48
#define BBX  64
#define FFX  32
#define LLX  (RR + OO - 1)    /* 79  */
#define RBr  (RR * BBX)       /* 2048 */
#define N6   (6 * HH)         /* 768 */

typedef unsigned short u16;
typedef __attribute__((ext_vector_type(8))) short short8;
typedef __attribute__((ext_vector_type(4))) float f32x4;

// ---- workspace layout (compile-time byte offsets, 256-aligned) ----
#define ALIGN256(x) (((x) + 255) & ~(size_t)255)
#define SZ_ABUF0  ((size_t)LLX * RBr * FFX * 2)
#define OFF_ABUF0 ((size_t)0)
#define OFF_WB0   ALIGN256(OFF_ABUF0 + SZ_ABUF0)
#define SZ_WB0    ((size_t)N6 * 288 * 2)
#define OFF_WB12  ALIGN256(OFF_WB0 + SZ_WB0)
#define SZ_WB12   ((size_t)2 * N6 * 512 * 2)
#define OFF_HZ    ALIGN256(OFF_WB12 + SZ_WB12)
#define SZ_HZ     ((size_t)NLAY * 2 * RBr * 256 * 2)   /* [l][slot][2048][256] bf16 */
#define OFF_HROW  (OFF_HZ + SZ_HZ)
#define SZ_HROW   ((size_t)NLAY * RBr * HH * 4)        /* [l][2048][128] f32 */
#define OFF_HCOL  (OFF_HROW + SZ_HROW)
#define SZ_HCOL   ((size_t)NLAY * 2 * RBr * HH * 4)    /* [l][slot][2048][128] f32 */
#define OFF_ACTV  (OFF_HCOL + SZ_HCOL)
#define SZ_ACTV   ((size_t)2 * 2 * RBr * 256 * 2)      /* [pair][slot][2048][256] bf16 */
#define SZ_STATE  (SZ_HZ + SZ_HROW + SZ_HCOL)          /* contiguous zero region */

__device__ __forceinline__ u16 f2b(float x) {
  uint32_t u = __float_as_uint(x);
  return (u16)((u + 0x7FFFu + ((u >> 16) & 1u)) >> 16);
}
__device__ __forceinline__ float sigmoidf_(float x) {
  return 1.0f / (1.0f + __expf(-x));
}
__device__ __forceinline__ float tanhf_(float x) {
  float e = __expf(2.0f * x);
  return 1.0f - 2.0f / (e + 1.0f);
}

// ---------------- prep: wavefront-shifted bf16 input ----------------
__global__ __launch_bounds__(256) void k_prep_input(const float* __restrict__ inp,
                                                    u16* __restrict__ abuf0) {
  int idx = blockIdx.x * 256 + threadIdx.x;
  if (idx >= LLX * RBr * FFX) return;
  int f   = idx & (FFX - 1);
  int row = (idx >> 5) & (RBr - 1);
  int s   = idx / (RBr * FFX);
  int g = row >> 6, b = row & 63;
  int o = s - g;
  float v = (o >= 0 && o < OO) ? inp[((b * RR + g) * OO + o) * FFX + f] : 0.0f;
  abuf0[idx] = f2b(v);
}

// ---------------- prep: weights f32 -> bf16 ----------------
__global__ __launch_bounds__(256) void k_prep_w(const float* __restrict__ Wf,
                                                const float* __restrict__ Wo,
                                                u16* __restrict__ w0,
                                                u16* __restrict__ w12) {
  int idx = blockIdx.x * 256 + threadIdx.x;
  const int n0 = N6 * 288;
  const int n12 = 2 * N6 * 512;
  if (idx < n0) w0[idx] = f2b(Wf[idx]);
  else if (idx < n0 + n12) w12[idx - n0] = f2b(Wo[idx - n0]);
}

// ---------------- zero all recurrent state (grid-stride, u32 words) -------
__global__ __launch_bounds__(256) void k_zero(uint32_t* __restrict__ p, size_t nwords) {
  size_t i = (size_t)blockIdx.x * 256 + threadIdx.x;
  size_t stride = (size_t)gridDim.x * 256;
  for (; i < nwords; i += stride) p[i] = 0u;
}

// ---------------- fused step body (GEMM + pointwise), one layer-slice -----
// Block: 512 threads = 8 waves; 32 rows x 768 cols.
// Wave w owns column fragments at cols w*16 + 128*m (m=0..5) -> after MFMA
// each lane holds all 6 gates for hidden index j = w*16 + (lane&15).
template <int KA>
__device__ __forceinline__ void step_body(
    const u16* __restrict__ Wb, const u16* __restrict__ asrc,
    const u16* __restrict__ hzR, u16* __restrict__ hzW,
    float* __restrict__ hrow, const float* __restrict__ hcolR,
    float* __restrict__ hcolW, const float* __restrict__ bias,
    u16* __restrict__ actv_out, float* __restrict__ out_all,
    float* __restrict__ hid_row, float* __restrict__ hid_col,
    int s, int layer, int m0) {
  constexpr int K   = 256 + KA;
  constexpr int NCH = K / 32;
  constexpr int LDA = K + 8;           // +16B pad: 2-way (free) bank pattern
  __shared__ u16 Alds[32 * LDA];

  const int tid = threadIdx.x;
  // ---- stage A tile (32 x K) to LDS: hz cols [0,256), asrc cols [256,K) ----
  constexpr int GPR = K / 8;           // 8-bf16 groups per row
  constexpr int TOT = 32 * GPR;
  for (int e = tid; e < TOT; e += 512) {
    int row = e / GPR, c8 = e - row * GPR;
    int col = c8 * 8;
    short8 v;
    if (col < 256) v = *(const short8*)&hzR[(m0 + row) * 256 + col];
    else           v = *(const short8*)&asrc[(m0 + row) * KA + (col - 256)];
    *(short8*)&Alds[row * LDA + col] = v;
  }
  __syncthreads();

  const int lane = tid & 63, w = tid >> 6;
  const int fr = lane & 15, kg = (lane >> 4) << 3;

  const u16* bptr[6];
#pragma unroll
  for (int m = 0; m < 6; ++m)
    bptr[m] = Wb + (size_t)(w * 16 + m * 128 + fr) * K + kg;
  const u16* aptr0 = &Alds[fr * LDA + kg];
  const u16* aptr1 = &Alds[(16 + fr) * LDA + kg];

  f32x4 z4 = {0.f, 0.f, 0.f, 0.f};
  f32x4 acc[2][6];
#pragma unroll
  for (int rf = 0; rf < 2; ++rf)
#pragma unroll
    for (int m = 0; m < 6; ++m) acc[rf][m] = z4;

#pragma unroll
  for (int kc = 0; kc < NCH; ++kc) {
    short8 a0 = *(const short8*)(aptr0 + kc * 32);
    short8 a1 = *(const short8*)(aptr1 + kc * 32);
#pragma unroll
    for (int m = 0; m < 6; ++m) {
      short8 b = *(const short8*)(bptr[m] + kc * 32);
      acc[0][m] = __builtin_amdgcn_mfma_f32_16x16x32_bf16(a0, b, acc[0][m], 0, 0, 0);
      acc[1][m] = __builtin_amdgcn_mfma_f32_16x16x32_bf16(a1, b, acc[1][m], 0, 0, 0);
    }
  }

  // ---- fused pointwise epilogue ----
  const int j = w * 16 + fr;           // hidden index, 0..127
  float bia[6];
#pragma unroll
  for (int m = 0; m < 6; ++m) bia[m] = bias[m * 128 + j];

#pragma unroll
  for (int rf = 0; rf < 2; ++rf) {
#pragma unroll
    for (int q = 0; q < 4; ++q) {
      int rl = rf * 16 + ((lane >> 4) << 2) + q;   // C layout: row=(lane>>4)*4+reg
      int row = m0 + rl;
      int g = row >> 6, b = row & 63;
      float m = (g <= s && s < RR) ? 1.0f : 0.0f;
      float ur  = sigmoidf_(acc[rf][0][q] + m * bia[0]);
      float orw = sigmoidf_(acc[rf][1][q] + m * bia[1]);
      float uc  = sigmoidf_(acc[rf][2][q] + m * bia[2]);
      float oc  = sigmoidf_(acc[rf][3][q] + m * bia[3]);
      float ir  = tanhf_(acc[rf][4][q] + m * bia[4]);
      float ic  = tanhf_(acc[rf][5][q] + m * bia[5]);
      float hr_o = hrow[row * HH + j];
      float hc_o = hcolR[row * HH + j];
      float hr_n = tanhf_((1.0f - ur) * hr_o + ur * ir) * orw;
      float hc_n = tanhf_((1.0f - uc) * hc_o + uc * ic) * oc;
      hrow[row * HH + j] = hr_n;
      int rp = (((g + 1) & (RR - 1)) << 6) + b;    // col-hidden rolls to next group
      hcolW[rp * HH + j] = hc_n;
      hzW[row * 256 + j] = f2b(hr_n);
      hzW[rp * 256 + HH + j] = f2b(hc_n);
      if (out_all) {
        out_all[((size_t)row * LLX + s) * 256 + j] = hr_n;
        out_all[((size_t)row * LLX + s) * 256 + HH + j] = hc_n;
      } else {
        actv_out[row * 256 + j] = f2b(hr_n);
        actv_out[row * 256 + HH + j] = f2b(hc_n);
      }
      if (s - g == OO - 1)
        hid_row[((size_t)(b * NLAY + layer) * RR + g) * HH + j] = hr_n;
      if (g == RR - 1 && s >= RR - 1)
        hid_col[((size_t)(b * NLAY + layer) * OO + (s - (RR - 1))) * HH + j] = hc_n;
    }
  }
}

// ---------------- one time-step: all 3 layers pipelined ----------------
__global__ __launch_bounds__(512) void k_step(char* __restrict__ ws,
                                              const float* __restrict__ Bias,
                                              float* __restrict__ out, int t) {
  const int layer = blockIdx.x >> 6;
  const int mblk  = blockIdx.x & 63;
  const int s = t - layer;
  if (s < 0 || s >= LLX) return;
  const int m0 = mblk * 32;
  const int sW = s & 1, sR = sW ^ 1;

  u16*   abuf0 = (u16*)(ws + OFF_ABUF0);
  u16*   wb0   = (u16*)(ws + OFF_WB0);
  u16*   wb12  = (u16*)(ws + OFF_WB12);
  u16*   hzR   = (u16*)(ws + OFF_HZ) + (size_t)(layer * 2 + sR) * RBr * 256;
  u16*   hzW   = (u16*)(ws + OFF_HZ) + (size_t)(layer * 2 + sW) * RBr * 256;
  float* hrow  = (float*)(ws + OFF_HROW) + (size_t)layer * RBr * HH;
  float* hcolR = (float*)(ws + OFF_HCOL) + (size_t)(layer * 2 + sR) * RBr * HH;
  float* hcolW = (float*)(ws + OFF_HCOL) + (size_t)(layer * 2 + sW) * RBr * HH;
  u16*   actvO = (layer < 2)
                   ? (u16*)(ws + OFF_ACTV) + (size_t)(layer * 2 + sW) * RBr * 256
                   : nullptr;
  float* out_all = out;
  float* hid_row = out + (size_t)RBr * LLX * 256;
  float* hid_col = hid_row + (size_t)BBX * NLAY * RR * HH;
  const float* bias_l = Bias + layer * N6;

  if (layer == 0) {
    const u16* asrc = abuf0 + (size_t)s * RBr * FFX;
    step_body<FFX>(wb0, asrc, hzR, hzW, hrow, hcolR, hcolW, bias_l,
                   actvO, nullptr, hid_row, hid_col, s, layer, m0);
  } else {
    const u16* Wb = wb12 + (size_t)(layer - 1) * N6 * 512;
    const u16* asrc = (u16*)(ws + OFF_ACTV) + (size_t)((layer - 1) * 2 + sW) * RBr * 256;
    step_body<256>(Wb, asrc, hzR, hzW, hrow, hcolR, hcolW, bias_l,
                   actvO, (layer == 2) ? out_all : nullptr,
                   hid_row, hid_col, s, layer, m0);
  }
}

extern "C" void kernel_launch(void* const* d_in, const int* in_sizes, int n_in,
                              void* d_out, int out_size, void* d_ws, size_t ws_size,
                              hipStream_t stream) {
  const float* inp  = (const float*)d_in[0];
  const float* Wf   = (const float*)d_in[1];
  const float* Wo   = (const float*)d_in[2];
  const float* Bias = (const float*)d_in[3];
  float* out = (float*)d_out;
  char* ws = (char*)d_ws;
  (void)in_sizes; (void)n_in; (void)out_size; (void)ws_size;

  k_prep_input<<<(LLX * RBr * FFX) / 256, 256, 0, stream>>>(inp, (u16*)(ws + OFF_ABUF0));
  k_prep_w<<<(N6 * 288 + 2 * N6 * 512) / 256, 256, 0, stream>>>(
      Wf, Wo, (u16*)(ws + OFF_WB0), (u16*)(ws + OFF_WB12));
  k_zero<<<2048, 256, 0, stream>>>((uint32_t*)(ws + OFF_HZ), SZ_STATE / 4);

  for (int t = 0; t <= LLX - 1 + (NLAY - 1); ++t)
    k_step<<<dim3(NLAY * 64), 512, 0, stream>>>(ws, Bias, out, t);
}